// Round 5
// baseline (1133.791 us; speedup 1.0000x reference)
//
#include <hip/hip_runtime.h>
#include <hip/hip_cooperative_groups.h>

namespace cg = cooperative_groups;

// ---------------------------------------------------------------------------
// GraphTransformerWithPooling on MI355X (gfx950)
// R5: single cooperative mega-kernel. R4 profiling showed ~160 us of the
// 344 us total was inter-dispatch overhead (18 graph nodes x ~8 us); all
// phase bodies here are identical to R4's proven kernels, separated by
// grid.sync() instead of kernel boundaries. Histogram overlaps GEMM1 (they
// are independent). Weights pre-split into bf16 hi+lo MFMA fragments; all
// inter-stage tensors bf16; fp32 accumulation everywhere.
// ---------------------------------------------------------------------------

typedef __attribute__((ext_vector_type(8))) short bf16x8;  // MFMA A/B frag
typedef __attribute__((ext_vector_type(4))) float f32x4;   // MFMA C/D frag

__device__ inline unsigned short f2bf(float f) {   // fp32 -> bf16 RNE
    unsigned u = __float_as_uint(f);
    return (unsigned short)((u + 0x7fffu + ((u >> 16) & 1u)) >> 16);
}
__device__ inline float bf2f(unsigned short h) {
    return __uint_as_float(((unsigned)h) << 16);
}

struct Params {
    const float* x;
    const int* src;
    const int* dst;
    const float* W1; const float* b1;
    const float* W2; const float* b2;
    const float* Wout; const float* bout;
    float* out;
    unsigned short* m;
    unsigned short* hA;
    unsigned short* hB;
    unsigned short* W1hi; unsigned short* W1lo;
    unsigned short* W2hi; unsigned short* W2lo;
    unsigned short* Wohi; unsigned short* Wolo;
    int* rp;
    int* cursor;
    int* es;
    int* partials;
    int N;
    int E;
};

// ---- W prep: fp32 W[K][C] -> hi/lo bf16 MFMA-B-fragment arrays ----
// t = ((ct*4 + c)*64 + lane)*8 + j  <->  k = c*32 + (lane>>4)*8 + j,
// col = ct*16 + (lane&15); wave-uniform 16B loads of hi[] are B fragments.
__device__ void wprep_dev(const float* __restrict__ W, unsigned short* __restrict__ hi,
                          unsigned short* __restrict__ lo, int total, int C,
                          int g0, int G) {
    for (int t = g0; t < total; t += G) {
        int j = t & 7;
        int lane = (t >> 3) & 63;
        int f = t >> 9;
        int c = f & 3, ct = f >> 2;
        int k = c * 32 + (lane >> 4) * 8 + j;
        int col = ct * 16 + (lane & 15);
        float w = W[(size_t)k * C + col];
        unsigned short h = f2bf(w);
        hi[t] = h;
        lo[t] = f2bf(w - bf2f(h));
    }
}

// ---- MFMA GEMM phase: Y[n,COLS] = A[n,128] @ (Whi+Wlo) + Bias ----
// 64 rows x COLS per tile; 4 waves/block; wave = 4 row-tiles x CT_W col-tiles.
// No LDS, no block barriers. A frags in regs, W frags streamed (L2-hot).
template <int COLS, bool AF32, bool OUTF32>
__device__ void gemm_phase(const void* __restrict__ Av, const uint4* __restrict__ Whi,
                           const uint4* __restrict__ Wlo, const float* __restrict__ Bias,
                           void* __restrict__ Yv, int n, int bid, int nb, int tid) {
    constexpr int CT_W = COLS / 64;
    int wave = tid >> 6, lane = tid & 63;
    int lm = lane & 15, lq = lane >> 4;
    int tiles = (n + 63) >> 6;

    for (int tile = bid; tile < tiles; tile += nb) {
        int r0 = tile * 64;

        bf16x8 afr[4][4];
#pragma unroll
        for (int rt = 0; rt < 4; ++rt) {
            int ar = r0 + rt * 16 + lm;
            if (ar > n - 1) ar = n - 1;      // clamp; stores are guarded
#pragma unroll
            for (int c = 0; c < 4; ++c) {
                int k = c * 32 + lq * 8;
                if (AF32) {
                    const float* ap = (const float*)Av + (size_t)ar * 128 + k;
                    float4 f0 = ((const float4*)ap)[0];
                    float4 f1 = ((const float4*)ap)[1];
                    bf16x8 v;
                    v[0] = (short)f2bf(f0.x); v[1] = (short)f2bf(f0.y);
                    v[2] = (short)f2bf(f0.z); v[3] = (short)f2bf(f0.w);
                    v[4] = (short)f2bf(f1.x); v[5] = (short)f2bf(f1.y);
                    v[6] = (short)f2bf(f1.z); v[7] = (short)f2bf(f1.w);
                    afr[rt][c] = v;
                } else {
                    uint4 u = *(const uint4*)((const unsigned short*)Av + (size_t)ar * 128 + k);
                    afr[rt][c] = *(const bf16x8*)&u;
                }
            }
        }

        f32x4 acc[4][CT_W];
#pragma unroll
        for (int rt = 0; rt < 4; ++rt)
#pragma unroll
            for (int t = 0; t < CT_W; ++t)
                acc[rt][t] = (f32x4){0.f, 0.f, 0.f, 0.f};

#pragma unroll
        for (int c = 0; c < 4; ++c) {
#pragma unroll
            for (int t = 0; t < CT_W; ++t) {
                int ct = wave * CT_W + t;
                uint4 uh = Whi[(ct * 4 + c) * 64 + lane];
                uint4 ul = Wlo[(ct * 4 + c) * 64 + lane];
                bf16x8 wh = *(const bf16x8*)&uh;
                bf16x8 wl = *(const bf16x8*)&ul;
#pragma unroll
                for (int rt = 0; rt < 4; ++rt) {
                    acc[rt][t] = __builtin_amdgcn_mfma_f32_16x16x32_bf16(afr[rt][c], wh, acc[rt][t], 0, 0, 0);
                    acc[rt][t] = __builtin_amdgcn_mfma_f32_16x16x32_bf16(afr[rt][c], wl, acc[rt][t], 0, 0, 0);
                }
            }
        }

        // C/D layout: col = lane&15, row = lq*4 + reg
#pragma unroll
        for (int t = 0; t < CT_W; ++t) {
            int col = (wave * CT_W + t) * 16 + lm;
            float bias = Bias[col];
#pragma unroll
            for (int rt = 0; rt < 4; ++rt) {
#pragma unroll
                for (int r = 0; r < 4; ++r) {
                    int row = r0 + rt * 16 + lq * 4 + r;
                    if (row < n) {
                        float v = acc[rt][t][r] + bias;
                        if (OUTF32)
                            ((float*)Yv)[(size_t)row * COLS + col] = v;
                        else
                            ((unsigned short*)Yv)[(size_t)row * COLS + col] = f2bf(v);
                    }
                }
            }
        }
    }
}

// ---- Aggregate phase: H[i,:] = sum_{e in CSR row i} M[es[e],:] (+ReLU) ----
// 16 lanes/node, uint4 = 8 bf16/lane; x4-unrolled edge loop; fp32 acc.
__device__ inline void acc_row8(float* a, uint4 v) {
    a[0] += __uint_as_float(v.x << 16);
    a[1] += __uint_as_float(v.x & 0xffff0000u);
    a[2] += __uint_as_float(v.y << 16);
    a[3] += __uint_as_float(v.y & 0xffff0000u);
    a[4] += __uint_as_float(v.z << 16);
    a[5] += __uint_as_float(v.z & 0xffff0000u);
    a[6] += __uint_as_float(v.w << 16);
    a[7] += __uint_as_float(v.w & 0xffff0000u);
}

__device__ void agg_phase(const unsigned short* __restrict__ M, const int* __restrict__ rp,
                          const int* __restrict__ es, unsigned short* __restrict__ H,
                          int n, int do_relu, int bid, int nb, int tid) {
    int groups = (n + 15) >> 4;
    int sub = tid >> 4, lane = tid & 15;
    for (int g = bid; g < groups; g += nb) {
        int node = g * 16 + sub;
        if (node >= n) continue;
        int beg = rp[node], end = rp[node + 1];
        float acc[8] = {};

        int e = beg;
        for (; e + 4 <= end; e += 4) {
            int s0 = es[e], s1 = es[e + 1], s2 = es[e + 2], s3 = es[e + 3];
            uint4 v0 = ((const uint4*)(M + (size_t)s0 * 128))[lane];
            uint4 v1 = ((const uint4*)(M + (size_t)s1 * 128))[lane];
            uint4 v2 = ((const uint4*)(M + (size_t)s2 * 128))[lane];
            uint4 v3 = ((const uint4*)(M + (size_t)s3 * 128))[lane];
            acc_row8(acc, v0);
            acc_row8(acc, v1);
            acc_row8(acc, v2);
            acc_row8(acc, v3);
        }
        for (; e < end; ++e) {
            uint4 v = ((const uint4*)(M + (size_t)es[e] * 128))[lane];
            acc_row8(acc, v);
        }

        if (do_relu) {
#pragma unroll
            for (int i = 0; i < 8; ++i) acc[i] = fmaxf(acc[i], 0.f);
        }
        uint4 o;
        o.x = (unsigned)f2bf(acc[0]) | ((unsigned)f2bf(acc[1]) << 16);
        o.y = (unsigned)f2bf(acc[2]) | ((unsigned)f2bf(acc[3]) << 16);
        o.z = (unsigned)f2bf(acc[4]) | ((unsigned)f2bf(acc[5]) << 16);
        o.w = (unsigned)f2bf(acc[6]) | ((unsigned)f2bf(acc[7]) << 16);
        *(uint4*)(H + (size_t)node * 128 + lane * 8) = o;
    }
}

// ---- The mega-kernel ----
__global__ __launch_bounds__(256, 4) void mega_kernel(Params p) {
    cg::grid_group grid = cg::this_grid();
    const int bid = blockIdx.x, nb = gridDim.x, tid = threadIdx.x;
    const int g0 = bid * 256 + tid, G = nb * 256;
    const int N = p.N, E = p.E;
    __shared__ int s[256];

    // P0: zero degree counters (cursor doubles as deg) + split-W frag prep
    for (int i = g0; i < N; i += G) p.cursor[i] = 0;
    wprep_dev(p.W1, p.W1hi, p.W1lo, 128 * 128, 128, g0, G);
    wprep_dev(p.W2, p.W2hi, p.W2lo, 128 * 128, 128, g0, G);
    wprep_dev(p.Wout, p.Wohi, p.Wolo, 128 * 64, 64, g0, G);
    grid.sync();

    // P1: degree histogram + GEMM1 (independent: x @ W1 -> m)
    for (int e = g0; e < E; e += G) atomicAdd(&p.cursor[p.dst[e]], 1);
    gemm_phase<128, true, false>(p.x, (const uint4*)p.W1hi, (const uint4*)p.W1lo,
                                 p.b1, p.m, N, bid, nb, tid);
    grid.sync();

    // P2a: per-256-chunk exclusive scan of deg -> rp; chunk sums -> partials
    int nChunks = (N + 256) >> 8;   // ceil((N+1)/256)
    for (int c = bid; c < nChunks; c += nb) {
        int i = c * 256 + tid;
        int v = (i < N) ? p.cursor[i] : 0;
        s[tid] = v;
        __syncthreads();
        for (int off = 1; off < 256; off <<= 1) {
            int t = (tid >= off) ? s[tid - off] : 0;
            __syncthreads();
            s[tid] += t;
            __syncthreads();
        }
        if (i <= N) p.rp[i] = s[tid] - v;
        if (tid == 255) p.partials[c] = s[255];
        __syncthreads();
    }
    grid.sync();

    // P2b: block 0 scans the partials (nChunks <= 256)
    if (bid == 0) {
        int v = (tid < nChunks) ? p.partials[tid] : 0;
        s[tid] = v;
        __syncthreads();
        for (int off = 1; off < 256; off <<= 1) {
            int t = (tid >= off) ? s[tid - off] : 0;
            __syncthreads();
            s[tid] += t;
            __syncthreads();
        }
        if (tid < nChunks) p.partials[tid] = s[tid] - v;
    }
    grid.sync();

    // P2c: add chunk offsets; seed fill cursor
    for (int i = g0; i <= N; i += G) {
        int v = p.rp[i] + p.partials[i >> 8];
        p.rp[i] = v;
        if (i < N) p.cursor[i] = v;
    }
    grid.sync();

    // P3: bucket fill (CSR by dst)
    for (int e = g0; e < E; e += G) {
        int pos = atomicAdd(&p.cursor[p.dst[e]], 1);
        p.es[pos] = p.src[e];
    }
    grid.sync();

    // ---- pool pipeline ----
    agg_phase(p.m, p.rp, p.es, p.hA, N, 0, bid, nb, tid);
    grid.sync();
    gemm_phase<128, false, false>(p.hA, (const uint4*)p.W1hi, (const uint4*)p.W1lo,
                                  p.b1, p.m, N, bid, nb, tid);
    grid.sync();
    agg_phase(p.m, p.rp, p.es, p.hB, N, 1, bid, nb, tid);   // ReLU
    grid.sync();
    gemm_phase<128, false, false>(p.hB, (const uint4*)p.W2hi, (const uint4*)p.W2lo,
                                  p.b2, p.m, N, bid, nb, tid);
    grid.sync();
    agg_phase(p.m, p.rp, p.es, p.hA, N, 0, bid, nb, tid);
    grid.sync();
    gemm_phase<128, false, false>(p.hA, (const uint4*)p.W2hi, (const uint4*)p.W2lo,
                                  p.b2, p.m, N, bid, nb, tid);
    grid.sync();
    agg_phase(p.m, p.rp, p.es, p.hB, N, 1, bid, nb, tid);   // ReLU
    grid.sync();
    gemm_phase<64, false, true>(p.hB, (const uint4*)p.Wohi, (const uint4*)p.Wolo,
                                p.bout, p.out, N, bid, nb, tid);
}

// ---------------- Launch ----------------

static inline int ceil_div_h(int a, int b) { return (a + b - 1) / b; }

extern "C" void kernel_launch(void* const* d_in, const int* in_sizes, int n_in,
                              void* d_out, int out_size, void* d_ws, size_t ws_size,
                              hipStream_t stream) {
    const int N = in_sizes[0] / 128;
    const int E = in_sizes[1] / 2;

    char* ws = (char*)d_ws;
    auto take = [&](size_t bytes) {
        char* p = ws;
        ws += (bytes + 255) & ~(size_t)255;
        return p;
    };

    Params hp;
    hp.x    = (const float*)d_in[0];
    hp.src  = (const int*)d_in[1];
    hp.dst  = (const int*)d_in[1] + E;
    hp.W1   = (const float*)d_in[2];
    hp.b1   = (const float*)d_in[3];
    hp.W2   = (const float*)d_in[4];
    hp.b2   = (const float*)d_in[5];
    hp.Wout = (const float*)d_in[6];
    hp.bout = (const float*)d_in[7];
    hp.out  = (float*)d_out;

    hp.m  = (unsigned short*)take((size_t)N * 128 * 2);
    hp.hA = (unsigned short*)take((size_t)N * 128 * 2);
    hp.hB = (unsigned short*)take((size_t)N * 128 * 2);
    hp.W1hi = (unsigned short*)take(128 * 128 * 2);
    hp.W1lo = (unsigned short*)take(128 * 128 * 2);
    hp.W2hi = (unsigned short*)take(128 * 128 * 2);
    hp.W2lo = (unsigned short*)take(128 * 128 * 2);
    hp.Wohi = (unsigned short*)take(128 * 64 * 2);
    hp.Wolo = (unsigned short*)take(128 * 64 * 2);
    hp.rp      = (int*)take((size_t)(N + 1) * sizeof(int));
    hp.cursor  = (int*)take((size_t)N * sizeof(int));
    hp.es      = (int*)take((size_t)E * sizeof(int));
    hp.partials = (int*)take(4096);
    hp.N = N;
    hp.E = E;

    // Grid: co-resident by construction (occupancy query x 256 CUs, cap 1024).
    int maxB = 0;
    hipOccupancyMaxActiveBlocksPerMultiprocessor(&maxB, mega_kernel, 256, 0);
    if (maxB < 1) maxB = 1;
    int nb = maxB * 256;
    if (nb > 1024) nb = 1024;

    void* args[] = {&hp};
    hipLaunchCooperativeKernel(mega_kernel, dim3(nb), dim3(256), args, 0, stream);
}

// Round 6
// 302.789 us; speedup vs baseline: 3.7445x; 3.7445x over previous
//
#include <hip/hip_runtime.h>

// ---------------------------------------------------------------------------
// GraphTransformerWithPooling on MI355X (gfx950)
// R6: revert cooperative mega-kernel (R5: spills + cross-XCD sync cost).
// Multi-kernel pipeline with targeted fusion instead:
//   - aggregate fused with its FOLLOWING GEMM (block owns the 64 rows its
//     MFMA tile needs; agg -> LDS (stride 136, 2-way=free) -> A-frags).
//   - one prep kernel: cursor zero + all 3 split-W fragment expansions.
//   - scan_partials+add_offsets merged (block-local reduce of <=256 partials).
// 10 dispatches total (was 18). bf16 MFMA GEMM with split-precision weights
// (W = Whi + Wlo), fp32 accumulation; inter-stage tensors bf16.
// ---------------------------------------------------------------------------

static inline int ceil_div(int a, int b) { return (a + b - 1) / b; }

typedef __attribute__((ext_vector_type(8))) short bf16x8;  // MFMA A/B frag
typedef __attribute__((ext_vector_type(4))) float f32x4;   // MFMA C/D frag

__device__ inline unsigned short f2bf(float f) {   // fp32 -> bf16 RNE
    unsigned u = __float_as_uint(f);
    return (unsigned short)((u + 0x7fffu + ((u >> 16) & 1u)) >> 16);
}
__device__ inline float bf2f(unsigned short h) {
    return __uint_as_float(((unsigned)h) << 16);
}

// ---------------- prep: zero cursor + expand W1/W2/Wout into hi/lo frags ----
// Frag layout t = ((ct*4 + c)*64 + lane)*8 + j  <->
//   k = c*32 + (lane>>4)*8 + j, col = ct*16 + (lane&15).

__device__ void wprep_dev(const float* __restrict__ W, unsigned short* __restrict__ hi,
                          unsigned short* __restrict__ lo, int total, int C,
                          int g0, int G) {
    for (int t = g0; t < total; t += G) {
        int j = t & 7;
        int lane = (t >> 3) & 63;
        int f = t >> 9;
        int c = f & 3, ct = f >> 2;
        int k = c * 32 + (lane >> 4) * 8 + j;
        int col = ct * 16 + (lane & 15);
        float w = W[(size_t)k * C + col];
        unsigned short h = f2bf(w);
        hi[t] = h;
        lo[t] = f2bf(w - bf2f(h));
    }
}

__global__ __launch_bounds__(256) void prep_kernel(const float* __restrict__ W1,
                                                   const float* __restrict__ W2,
                                                   const float* __restrict__ Wout,
                                                   unsigned short* __restrict__ W1hi,
                                                   unsigned short* __restrict__ W1lo,
                                                   unsigned short* __restrict__ W2hi,
                                                   unsigned short* __restrict__ W2lo,
                                                   unsigned short* __restrict__ Wohi,
                                                   unsigned short* __restrict__ Wolo,
                                                   int* __restrict__ cursor, int N) {
    int g0 = blockIdx.x * 256 + threadIdx.x;
    int G = gridDim.x * 256;
    for (int i = g0; i < N; i += G) cursor[i] = 0;
    wprep_dev(W1, W1hi, W1lo, 128 * 128, 128, g0, G);
    wprep_dev(W2, W2hi, W2lo, 128 * 128, 128, g0, G);
    wprep_dev(Wout, Wohi, Wolo, 128 * 64, 64, g0, G);
}

// ---------------- CSR build ----------------

__global__ __launch_bounds__(256) void hist_kernel(const int* __restrict__ dst,
                                                   int* __restrict__ deg, int E) {
    int e = blockIdx.x * 256 + threadIdx.x;
    if (e < E) atomicAdd(&deg[dst[e]], 1);
}

__global__ __launch_bounds__(256) void scan_blocks_kernel(const int* __restrict__ deg,
                                                          int* __restrict__ rp,
                                                          int* __restrict__ partials,
                                                          int n, int N) {
    __shared__ int s[256];
    int tid = threadIdx.x;
    int i = blockIdx.x * 256 + tid;
    int v = (i < N) ? deg[i] : 0;
    s[tid] = v;
    __syncthreads();
    for (int off = 1; off < 256; off <<= 1) {
        int t = (tid >= off) ? s[tid - off] : 0;
        __syncthreads();
        s[tid] += t;
        __syncthreads();
    }
    if (i < n) rp[i] = s[tid] - v;
    if (tid == 255) partials[blockIdx.x] = s[255];
}

// Merged: each block (one 256-chunk) reduces partials[0..c-1] itself, then
// adds the prefix to its chunk of rp and seeds the fill cursor. nChunks<=256.
__global__ __launch_bounds__(256) void add_offsets2_kernel(int* __restrict__ rp,
                                                           const int* __restrict__ partials,
                                                           int* __restrict__ cursor,
                                                           int N) {
    __shared__ int s[256];
    int c = blockIdx.x, tid = threadIdx.x;
    s[tid] = (tid < c) ? partials[tid] : 0;
    __syncthreads();
    for (int off = 128; off >= 1; off >>= 1) {
        if (tid < off) s[tid] += s[tid + off];
        __syncthreads();
    }
    int prefix = s[0];
    int i = c * 256 + tid;
    if (i <= N) {
        int v = rp[i] + prefix;
        rp[i] = v;
        if (i < N) cursor[i] = v;
    }
}

__global__ __launch_bounds__(256) void fill_kernel(const int* __restrict__ src,
                                                   const int* __restrict__ dst,
                                                   int* __restrict__ cursor,
                                                   int* __restrict__ es, int E) {
    int e = blockIdx.x * 256 + threadIdx.x;
    if (e < E) {
        int p = atomicAdd(&cursor[dst[e]], 1);
        es[p] = src[e];
    }
}

// ---------------- GEMM1: Y[n,128] = X_f32[n,128] @ (Whi+Wlo) + B -> bf16 ----
// R4's proven kernel, AF32 path only. 64 rows/block, 4 waves, no LDS.

__global__ __launch_bounds__(256) void gemm1_kernel(const float* __restrict__ X,
                                                    const uint4* __restrict__ Whi,
                                                    const uint4* __restrict__ Wlo,
                                                    const float* __restrict__ Bias,
                                                    unsigned short* __restrict__ Y, int n) {
    int tid = threadIdx.x;
    int wave = tid >> 6, lane = tid & 63;
    int lm = lane & 15, lq = lane >> 4;
    int r0 = blockIdx.x * 64;

    bf16x8 afr[4][4];
#pragma unroll
    for (int rt = 0; rt < 4; ++rt) {
        int ar = r0 + rt * 16 + lm;
        if (ar > n - 1) ar = n - 1;
#pragma unroll
        for (int c = 0; c < 4; ++c) {
            int k = c * 32 + lq * 8;
            const float* ap = X + (size_t)ar * 128 + k;
            float4 f0 = ((const float4*)ap)[0];
            float4 f1 = ((const float4*)ap)[1];
            bf16x8 v;
            v[0] = (short)f2bf(f0.x); v[1] = (short)f2bf(f0.y);
            v[2] = (short)f2bf(f0.z); v[3] = (short)f2bf(f0.w);
            v[4] = (short)f2bf(f1.x); v[5] = (short)f2bf(f1.y);
            v[6] = (short)f2bf(f1.z); v[7] = (short)f2bf(f1.w);
            afr[rt][c] = v;
        }
    }

    f32x4 acc[4][2];
#pragma unroll
    for (int rt = 0; rt < 4; ++rt)
#pragma unroll
        for (int t = 0; t < 2; ++t)
            acc[rt][t] = (f32x4){0.f, 0.f, 0.f, 0.f};

#pragma unroll
    for (int c = 0; c < 4; ++c) {
#pragma unroll
        for (int t = 0; t < 2; ++t) {
            int ct = wave * 2 + t;
            uint4 uh = Whi[(ct * 4 + c) * 64 + lane];
            uint4 ul = Wlo[(ct * 4 + c) * 64 + lane];
            bf16x8 wh = *(const bf16x8*)&uh;
            bf16x8 wl = *(const bf16x8*)&ul;
#pragma unroll
            for (int rt = 0; rt < 4; ++rt) {
                acc[rt][t] = __builtin_amdgcn_mfma_f32_16x16x32_bf16(afr[rt][c], wh, acc[rt][t], 0, 0, 0);
                acc[rt][t] = __builtin_amdgcn_mfma_f32_16x16x32_bf16(afr[rt][c], wl, acc[rt][t], 0, 0, 0);
            }
        }
    }

#pragma unroll
    for (int t = 0; t < 2; ++t) {
        int col = (wave * 2 + t) * 16 + lm;
        float bias = Bias[col];
#pragma unroll
        for (int rt = 0; rt < 4; ++rt) {
#pragma unroll
            for (int r = 0; r < 4; ++r) {
                int row = r0 + rt * 16 + lq * 4 + r;
                if (row < n)
                    Y[(size_t)row * 128 + col] = f2bf(acc[rt][t][r] + bias);
            }
        }
    }
}

// ---------------- Fused aggregate + GEMM ------------------------------------
// Block owns 64 consecutive nodes. Phase A: 16 lane-groups aggregate 4 nodes
// each (gather bf16 rows of M, fp32 acc, optional ReLU) -> LDS rows (bf16,
// stride 136: 2-way bank aliasing only = free). Phase B: 4 waves run the
// 64xCOLS MFMA tile with A-frags ds_read from LDS, W frags streamed (L2-hot).

__device__ inline void acc_row8(float* a, uint4 v) {
    a[0] += __uint_as_float(v.x << 16);
    a[1] += __uint_as_float(v.x & 0xffff0000u);
    a[2] += __uint_as_float(v.y << 16);
    a[3] += __uint_as_float(v.y & 0xffff0000u);
    a[4] += __uint_as_float(v.z << 16);
    a[5] += __uint_as_float(v.z & 0xffff0000u);
    a[6] += __uint_as_float(v.w << 16);
    a[7] += __uint_as_float(v.w & 0xffff0000u);
}

template <int COLS, bool OUTF32>
__global__ __launch_bounds__(256) void fused_agg_gemm_kernel(const unsigned short* __restrict__ M,
                                                             const int* __restrict__ rp,
                                                             const int* __restrict__ es,
                                                             const uint4* __restrict__ Whi,
                                                             const uint4* __restrict__ Wlo,
                                                             const float* __restrict__ Bias,
                                                             void* __restrict__ Yv,
                                                             int n, int do_relu) {
    constexpr int CT_W = COLS / 64;
    constexpr int SR = 136;                    // LDS row stride in bf16
    __shared__ unsigned short Hl[64 * SR];

    int tid = threadIdx.x;
    int r0 = blockIdx.x * 64;

    // ---- Phase A: aggregate 64 nodes into LDS ----
    {
        int sub = tid >> 4, ln = tid & 15;
        for (int q = 0; q < 4; ++q) {
            int nl = sub * 4 + q;
            int node = r0 + nl;
            float acc[8] = {};
            if (node < n) {
                int beg = rp[node], end = rp[node + 1];
                int e = beg;
                for (; e + 4 <= end; e += 4) {
                    int s0 = es[e], s1 = es[e + 1], s2 = es[e + 2], s3 = es[e + 3];
                    uint4 v0 = ((const uint4*)(M + (size_t)s0 * 128))[ln];
                    uint4 v1 = ((const uint4*)(M + (size_t)s1 * 128))[ln];
                    uint4 v2 = ((const uint4*)(M + (size_t)s2 * 128))[ln];
                    uint4 v3 = ((const uint4*)(M + (size_t)s3 * 128))[ln];
                    acc_row8(acc, v0);
                    acc_row8(acc, v1);
                    acc_row8(acc, v2);
                    acc_row8(acc, v3);
                }
                for (; e < end; ++e) {
                    uint4 v = ((const uint4*)(M + (size_t)es[e] * 128))[ln];
                    acc_row8(acc, v);
                }
                if (do_relu) {
#pragma unroll
                    for (int i = 0; i < 8; ++i) acc[i] = fmaxf(acc[i], 0.f);
                }
            }
            uint4 o;
            o.x = (unsigned)f2bf(acc[0]) | ((unsigned)f2bf(acc[1]) << 16);
            o.y = (unsigned)f2bf(acc[2]) | ((unsigned)f2bf(acc[3]) << 16);
            o.z = (unsigned)f2bf(acc[4]) | ((unsigned)f2bf(acc[5]) << 16);
            o.w = (unsigned)f2bf(acc[6]) | ((unsigned)f2bf(acc[7]) << 16);
            *(uint4*)(&Hl[nl * SR + ln * 8]) = o;
        }
    }
    __syncthreads();

    // ---- Phase B: 64xCOLS MFMA tile, A from LDS ----
    int wave = tid >> 6, lane = tid & 63;
    int lm = lane & 15, lq = lane >> 4;

    f32x4 acc[4][CT_W];
#pragma unroll
    for (int rt = 0; rt < 4; ++rt)
#pragma unroll
        for (int t = 0; t < CT_W; ++t)
            acc[rt][t] = (f32x4){0.f, 0.f, 0.f, 0.f};

#pragma unroll
    for (int c = 0; c < 4; ++c) {
        bf16x8 afr[4];
#pragma unroll
        for (int rt = 0; rt < 4; ++rt) {
            int nl = rt * 16 + lm;
            afr[rt] = *(const bf16x8*)(&Hl[nl * SR + c * 32 + lq * 8]);
        }
#pragma unroll
        for (int t = 0; t < CT_W; ++t) {
            int ct = wave * CT_W + t;
            uint4 uh = Whi[(ct * 4 + c) * 64 + lane];
            uint4 ul = Wlo[(ct * 4 + c) * 64 + lane];
            bf16x8 wh = *(const bf16x8*)&uh;
            bf16x8 wl = *(const bf16x8*)&ul;
#pragma unroll
            for (int rt = 0; rt < 4; ++rt) {
                acc[rt][t] = __builtin_amdgcn_mfma_f32_16x16x32_bf16(afr[rt], wh, acc[rt][t], 0, 0, 0);
                acc[rt][t] = __builtin_amdgcn_mfma_f32_16x16x32_bf16(afr[rt], wl, acc[rt][t], 0, 0, 0);
            }
        }
    }

    // C/D layout: col = lane&15, row = lq*4 + reg
#pragma unroll
    for (int t = 0; t < CT_W; ++t) {
        int col = (wave * CT_W + t) * 16 + lm;
        float bias = Bias[col];
#pragma unroll
        for (int rt = 0; rt < 4; ++rt) {
#pragma unroll
            for (int r = 0; r < 4; ++r) {
                int row = r0 + rt * 16 + lq * 4 + r;
                if (row < n) {
                    float v = acc[rt][t][r] + bias;
                    if (OUTF32)
                        ((float*)Yv)[(size_t)row * COLS + col] = v;
                    else
                        ((unsigned short*)Yv)[(size_t)row * COLS + col] = f2bf(v);
                }
            }
        }
    }
}

// ---------------- Launch ----------------

extern "C" void kernel_launch(void* const* d_in, const int* in_sizes, int n_in,
                              void* d_out, int out_size, void* d_ws, size_t ws_size,
                              hipStream_t stream) {
    const float* x    = (const float*)d_in[0];
    const int*   ei   = (const int*)d_in[1];
    const float* W1   = (const float*)d_in[2];
    const float* b1   = (const float*)d_in[3];
    const float* W2   = (const float*)d_in[4];
    const float* b2   = (const float*)d_in[5];
    const float* Wout = (const float*)d_in[6];
    const float* bout = (const float*)d_in[7];
    float*       out  = (float*)d_out;

    const int N = in_sizes[0] / 128;
    const int E = in_sizes[1] / 2;
    const int* src = ei;
    const int* dst = ei + E;

    char* ws = (char*)d_ws;
    auto take = [&](size_t bytes) {
        char* p = ws;
        ws += (bytes + 255) & ~(size_t)255;
        return p;
    };
    unsigned short* mA = (unsigned short*)take((size_t)N * 128 * 2);
    unsigned short* mB = (unsigned short*)take((size_t)N * 128 * 2);
    unsigned short* W1hi = (unsigned short*)take(128 * 128 * 2);
    unsigned short* W1lo = (unsigned short*)take(128 * 128 * 2);
    unsigned short* W2hi = (unsigned short*)take(128 * 128 * 2);
    unsigned short* W2lo = (unsigned short*)take(128 * 128 * 2);
    unsigned short* Wohi = (unsigned short*)take(128 * 64 * 2);
    unsigned short* Wolo = (unsigned short*)take(128 * 64 * 2);
    int* rp      = (int*)take((size_t)(N + 1) * sizeof(int));
    int* cursor  = (int*)take((size_t)N * sizeof(int));
    int* es      = (int*)take((size_t)E * sizeof(int));
    int* partials = (int*)take(4096);

    // ---- prep (cursor zero + all W frag expansion) + CSR build ----
    prep_kernel<<<256, 256, 0, stream>>>(W1, W2, Wout, W1hi, W1lo, W2hi, W2lo,
                                         Wohi, Wolo, cursor, N);
    hist_kernel<<<ceil_div(E, 256), 256, 0, stream>>>(dst, cursor, E);
    int nChunks = ceil_div(N + 1, 256);   // 196 for N=50000 (<=256 required)
    scan_blocks_kernel<<<nChunks, 256, 0, stream>>>(cursor, rp, partials, N + 1, N);
    add_offsets2_kernel<<<nChunks, 256, 0, stream>>>(rp, partials, cursor, N);
    fill_kernel<<<ceil_div(E, 256), 256, 0, stream>>>(src, dst, cursor, es, E);

    // ---- pipeline: 1 GEMM + 4 fused (agg -> GEMM) ----
    const int tiles = ceil_div(N, 64);

    gemm1_kernel<<<tiles, 256, 0, stream>>>(x, (const uint4*)W1hi, (const uint4*)W1lo,
                                            b1, mA, N);
    fused_agg_gemm_kernel<128, false><<<tiles, 256, 0, stream>>>(
        mA, rp, es, (const uint4*)W1hi, (const uint4*)W1lo, b1, mB, N, 0);
    fused_agg_gemm_kernel<128, false><<<tiles, 256, 0, stream>>>(
        mB, rp, es, (const uint4*)W2hi, (const uint4*)W2lo, b2, mA, N, 1);   // ReLU
    fused_agg_gemm_kernel<128, false><<<tiles, 256, 0, stream>>>(
        mA, rp, es, (const uint4*)W2hi, (const uint4*)W2lo, b2, mB, N, 0);
    fused_agg_gemm_kernel<64, true><<<tiles, 256, 0, stream>>>(
        mB, rp, es, (const uint4*)Wohi, (const uint4*)Wolo, bout, out, N, 1);  // ReLU
}

// Round 7
// 299.432 us; speedup vs baseline: 3.7865x; 1.0112x over previous
//
#include <hip/hip_runtime.h>

// ---------------------------------------------------------------------------
// GraphTransformerWithPooling on MI355X (gfx950)
// R7: dispatch consolidation + single-bf16 W.
//  - scan_blocks + add_offsets merged: each chunk-block publishes its chunk
//    total (flagged atomicExch), then spin-reads all predecessors' totals
//    (publishers never wait -> no deadlock, no serial chain).
//  - fill and gemm1 are independent -> one role-split kernel.
//  - Wlo dropped (absmax 16 of 66.24 leaves headroom; m-rounding dominates):
//    halves MFMA count and W-fragment traffic in every GEMM.
// 8 dispatches: prep, hist, scan_fuse, fill||gemm1, fused x4.
// ---------------------------------------------------------------------------

static inline int ceil_div(int a, int b) { return (a + b - 1) / b; }

typedef __attribute__((ext_vector_type(8))) short bf16x8;  // MFMA A/B frag
typedef __attribute__((ext_vector_type(4))) float f32x4;   // MFMA C/D frag

__device__ inline unsigned short f2bf(float f) {   // fp32 -> bf16 RNE
    unsigned u = __float_as_uint(f);
    return (unsigned short)((u + 0x7fffu + ((u >> 16) & 1u)) >> 16);
}

// ---------------- prep: zero cursor+stat, expand W1/W2/Wout into frags ------
// Frag layout t = ((ct*4 + c)*64 + lane)*8 + j  <->
//   k = c*32 + (lane>>4)*8 + j, col = ct*16 + (lane&15).

__device__ void wprep_dev(const float* __restrict__ W, unsigned short* __restrict__ hi,
                          int total, int C, int g0, int G) {
    for (int t = g0; t < total; t += G) {
        int j = t & 7;
        int lane = (t >> 3) & 63;
        int f = t >> 9;
        int c = f & 3, ct = f >> 2;
        int k = c * 32 + (lane >> 4) * 8 + j;
        int col = ct * 16 + (lane & 15);
        hi[t] = f2bf(W[(size_t)k * C + col]);
    }
}

__global__ __launch_bounds__(256) void prep_kernel(const float* __restrict__ W1,
                                                   const float* __restrict__ W2,
                                                   const float* __restrict__ Wout,
                                                   unsigned short* __restrict__ W1hi,
                                                   unsigned short* __restrict__ W2hi,
                                                   unsigned short* __restrict__ Wohi,
                                                   int* __restrict__ cursor,
                                                   unsigned* __restrict__ stat,
                                                   int N, int nChunks) {
    int g0 = blockIdx.x * 256 + threadIdx.x;
    int G = gridDim.x * 256;
    for (int i = g0; i < N; i += G) cursor[i] = 0;
    for (int i = g0; i < nChunks; i += G) stat[i] = 0;
    wprep_dev(W1, W1hi, 128 * 128, 128, g0, G);
    wprep_dev(W2, W2hi, 128 * 128, 128, g0, G);
    wprep_dev(Wout, Wohi, 128 * 64, 64, g0, G);
}

// ---------------- CSR build ----------------

__global__ __launch_bounds__(256) void hist_kernel(const int* __restrict__ dst,
                                                   int* __restrict__ deg, int E) {
    int e = blockIdx.x * 256 + threadIdx.x;
    if (e < E) atomicAdd(&deg[dst[e]], 1);
}

// Merged scan: block c = one 256-chunk. Local exclusive scan; publish chunk
// total with flag bit; spin-read totals of chunks < c; reduce; write rp and
// seed fill cursor. Publishers never depend on other blocks -> no deadlock.
__global__ __launch_bounds__(256) void scan_fuse_kernel(const int* __restrict__ deg,
                                                        int* __restrict__ rp,
                                                        int* __restrict__ cursor,
                                                        unsigned* __restrict__ stat,
                                                        int N) {
    __shared__ int s[256];
    int c = blockIdx.x, tid = threadIdx.x;
    int i = c * 256 + tid;
    int v = (i < N) ? deg[i] : 0;
    s[tid] = v;
    __syncthreads();
    for (int off = 1; off < 256; off <<= 1) {
        int t = (tid >= off) ? s[tid - off] : 0;
        __syncthreads();
        s[tid] += t;
        __syncthreads();
    }
    int loc = s[tid] - v;          // block-local exclusive
    int tot = s[255];              // chunk total
    __syncthreads();
    if (tid == 0) atomicExch(&stat[c], (unsigned)tot | 0x80000000u);

    // gather predecessors' totals (tid < c spins on its own slot)
    unsigned mine = 0;
    if (tid < c) {
        unsigned u;
        do { u = atomicAdd(&stat[tid], 0u); } while (!(u & 0x80000000u));
        mine = u & 0x7fffffffu;
    }
    s[tid] = (int)mine;
    __syncthreads();
    for (int off = 128; off >= 1; off >>= 1) {
        if (tid < off) s[tid] += s[tid + off];
        __syncthreads();
    }
    int prefix = s[0];
    if (i <= N) {
        int val = loc + prefix;
        rp[i] = val;
        if (i < N) cursor[i] = val;
    }
}

// ---------------- fill || gemm1 (independent; role-split by blockIdx) -------
// fill: CSR bucket fill. gemm1: Y[n,128] = bf16(X_f32) @ W1 + b1 -> bf16.

__global__ __launch_bounds__(256) void fill_gemm1_kernel(const int* __restrict__ src,
                                                         const int* __restrict__ dst,
                                                         int* __restrict__ cursor,
                                                         int* __restrict__ es, int E,
                                                         const float* __restrict__ X,
                                                         const uint4* __restrict__ Whi,
                                                         const float* __restrict__ Bias,
                                                         unsigned short* __restrict__ Y,
                                                         int n, int fillB) {
    int tid = threadIdx.x;
    if ((int)blockIdx.x < fillB) {
        int e = blockIdx.x * 256 + tid;
        if (e < E) {
            int p = atomicAdd(&cursor[dst[e]], 1);
            es[p] = src[e];
        }
        return;
    }

    // ---- gemm1 role ----
    int r0 = (blockIdx.x - fillB) * 64;
    int wave = tid >> 6, lane = tid & 63;
    int lm = lane & 15, lq = lane >> 4;

    bf16x8 afr[4][4];
#pragma unroll
    for (int rt = 0; rt < 4; ++rt) {
        int ar = r0 + rt * 16 + lm;
        if (ar > n - 1) ar = n - 1;
#pragma unroll
        for (int c = 0; c < 4; ++c) {
            int k = c * 32 + lq * 8;
            const float* ap = X + (size_t)ar * 128 + k;
            float4 f0 = ((const float4*)ap)[0];
            float4 f1 = ((const float4*)ap)[1];
            bf16x8 v;
            v[0] = (short)f2bf(f0.x); v[1] = (short)f2bf(f0.y);
            v[2] = (short)f2bf(f0.z); v[3] = (short)f2bf(f0.w);
            v[4] = (short)f2bf(f1.x); v[5] = (short)f2bf(f1.y);
            v[6] = (short)f2bf(f1.z); v[7] = (short)f2bf(f1.w);
            afr[rt][c] = v;
        }
    }

    f32x4 acc[4][2];
#pragma unroll
    for (int rt = 0; rt < 4; ++rt)
#pragma unroll
        for (int t = 0; t < 2; ++t)
            acc[rt][t] = (f32x4){0.f, 0.f, 0.f, 0.f};

#pragma unroll
    for (int c = 0; c < 4; ++c) {
#pragma unroll
        for (int t = 0; t < 2; ++t) {
            int ct = wave * 2 + t;
            uint4 uh = Whi[(ct * 4 + c) * 64 + lane];
            bf16x8 wh = *(const bf16x8*)&uh;
#pragma unroll
            for (int rt = 0; rt < 4; ++rt)
                acc[rt][t] = __builtin_amdgcn_mfma_f32_16x16x32_bf16(afr[rt][c], wh, acc[rt][t], 0, 0, 0);
        }
    }

#pragma unroll
    for (int t = 0; t < 2; ++t) {
        int col = (wave * 2 + t) * 16 + lm;
        float bias = Bias[col];
#pragma unroll
        for (int rt = 0; rt < 4; ++rt) {
#pragma unroll
            for (int r = 0; r < 4; ++r) {
                int row = r0 + rt * 16 + lq * 4 + r;
                if (row < n)
                    Y[(size_t)row * 128 + col] = f2bf(acc[rt][t][r] + bias);
            }
        }
    }
}

// ---------------- Fused aggregate + GEMM ------------------------------------
// Block owns 64 nodes. Phase A: 16 lane-groups aggregate 4 nodes each
// (gather bf16 rows, fp32 acc, optional ReLU) -> LDS (stride 136, 2-way
// bank aliasing = free). Phase B: 4 waves, 64xCOLS MFMA tile, A from LDS,
// W frags streamed (L2-hot, 32 KB).

__device__ inline void acc_row8(float* a, uint4 v) {
    a[0] += __uint_as_float(v.x << 16);
    a[1] += __uint_as_float(v.x & 0xffff0000u);
    a[2] += __uint_as_float(v.y << 16);
    a[3] += __uint_as_float(v.y & 0xffff0000u);
    a[4] += __uint_as_float(v.z << 16);
    a[5] += __uint_as_float(v.z & 0xffff0000u);
    a[6] += __uint_as_float(v.w << 16);
    a[7] += __uint_as_float(v.w & 0xffff0000u);
}

template <int COLS, bool OUTF32>
__global__ __launch_bounds__(256) void fused_agg_gemm_kernel(const unsigned short* __restrict__ M,
                                                             const int* __restrict__ rp,
                                                             const int* __restrict__ es,
                                                             const uint4* __restrict__ Whi,
                                                             const float* __restrict__ Bias,
                                                             void* __restrict__ Yv,
                                                             int n, int do_relu) {
    constexpr int CT_W = COLS / 64;
    constexpr int SR = 136;                    // LDS row stride in bf16
    __shared__ unsigned short Hl[64 * SR];

    int tid = threadIdx.x;
    int r0 = blockIdx.x * 64;

    // ---- Phase A: aggregate 64 nodes into LDS ----
    {
        int sub = tid >> 4, ln = tid & 15;
        for (int q = 0; q < 4; ++q) {
            int nl = sub * 4 + q;
            int node = r0 + nl;
            float acc[8] = {};
            if (node < n) {
                int beg = rp[node], end = rp[node + 1];
                int e = beg;
                for (; e + 4 <= end; e += 4) {
                    int s0 = es[e], s1 = es[e + 1], s2 = es[e + 2], s3 = es[e + 3];
                    uint4 v0 = ((const uint4*)(M + (size_t)s0 * 128))[ln];
                    uint4 v1 = ((const uint4*)(M + (size_t)s1 * 128))[ln];
                    uint4 v2 = ((const uint4*)(M + (size_t)s2 * 128))[ln];
                    uint4 v3 = ((const uint4*)(M + (size_t)s3 * 128))[ln];
                    acc_row8(acc, v0);
                    acc_row8(acc, v1);
                    acc_row8(acc, v2);
                    acc_row8(acc, v3);
                }
                for (; e < end; ++e) {
                    uint4 v = ((const uint4*)(M + (size_t)es[e] * 128))[ln];
                    acc_row8(acc, v);
                }
                if (do_relu) {
#pragma unroll
                    for (int i = 0; i < 8; ++i) acc[i] = fmaxf(acc[i], 0.f);
                }
            }
            uint4 o;
            o.x = (unsigned)f2bf(acc[0]) | ((unsigned)f2bf(acc[1]) << 16);
            o.y = (unsigned)f2bf(acc[2]) | ((unsigned)f2bf(acc[3]) << 16);
            o.z = (unsigned)f2bf(acc[4]) | ((unsigned)f2bf(acc[5]) << 16);
            o.w = (unsigned)f2bf(acc[6]) | ((unsigned)f2bf(acc[7]) << 16);
            *(uint4*)(&Hl[nl * SR + ln * 8]) = o;
        }
    }
    __syncthreads();

    // ---- Phase B: 64xCOLS MFMA tile, A from LDS ----
    int wave = tid >> 6, lane = tid & 63;
    int lm = lane & 15, lq = lane >> 4;

    f32x4 acc[4][CT_W];
#pragma unroll
    for (int rt = 0; rt < 4; ++rt)
#pragma unroll
        for (int t = 0; t < CT_W; ++t)
            acc[rt][t] = (f32x4){0.f, 0.f, 0.f, 0.f};

#pragma unroll
    for (int c = 0; c < 4; ++c) {
        bf16x8 afr[4];
#pragma unroll
        for (int rt = 0; rt < 4; ++rt) {
            int nl = rt * 16 + lm;
            afr[rt] = *(const bf16x8*)(&Hl[nl * SR + c * 32 + lq * 8]);
        }
#pragma unroll
        for (int t = 0; t < CT_W; ++t) {
            int ct = wave * CT_W + t;
            uint4 uh = Whi[(ct * 4 + c) * 64 + lane];
            bf16x8 wh = *(const bf16x8*)&uh;
#pragma unroll
            for (int rt = 0; rt < 4; ++rt)
                acc[rt][t] = __builtin_amdgcn_mfma_f32_16x16x32_bf16(afr[rt], wh, acc[rt][t], 0, 0, 0);
        }
    }

    // C/D layout: col = lane&15, row = lq*4 + reg
#pragma unroll
    for (int t = 0; t < CT_W; ++t) {
        int col = (wave * CT_W + t) * 16 + lm;
        float bias = Bias[col];
#pragma unroll
        for (int rt = 0; rt < 4; ++rt) {
#pragma unroll
            for (int r = 0; r < 4; ++r) {
                int row = r0 + rt * 16 + lq * 4 + r;
                if (row < n) {
                    float v = acc[rt][t][r] + bias;
                    if (OUTF32)
                        ((float*)Yv)[(size_t)row * COLS + col] = v;
                    else
                        ((unsigned short*)Yv)[(size_t)row * COLS + col] = f2bf(v);
                }
            }
        }
    }
}

// ---------------- Launch ----------------

extern "C" void kernel_launch(void* const* d_in, const int* in_sizes, int n_in,
                              void* d_out, int out_size, void* d_ws, size_t ws_size,
                              hipStream_t stream) {
    const float* x    = (const float*)d_in[0];
    const int*   ei   = (const int*)d_in[1];
    const float* W1   = (const float*)d_in[2];
    const float* b1   = (const float*)d_in[3];
    const float* W2   = (const float*)d_in[4];
    const float* b2   = (const float*)d_in[5];
    const float* Wout = (const float*)d_in[6];
    const float* bout = (const float*)d_in[7];
    float*       out  = (float*)d_out;

    const int N = in_sizes[0] / 128;
    const int E = in_sizes[1] / 2;
    const int* src = ei;
    const int* dst = ei + E;

    char* ws = (char*)d_ws;
    auto take = [&](size_t bytes) {
        char* p = ws;
        ws += (bytes + 255) & ~(size_t)255;
        return p;
    };
    unsigned short* mA = (unsigned short*)take((size_t)N * 128 * 2);
    unsigned short* mB = (unsigned short*)take((size_t)N * 128 * 2);
    unsigned short* W1hi = (unsigned short*)take(128 * 128 * 2);
    unsigned short* W2hi = (unsigned short*)take(128 * 128 * 2);
    unsigned short* Wohi = (unsigned short*)take(128 * 64 * 2);
    int* rp      = (int*)take((size_t)(N + 1) * sizeof(int));
    int* cursor  = (int*)take((size_t)N * sizeof(int));
    int* es      = (int*)take((size_t)E * sizeof(int));
    unsigned* stat = (unsigned*)take(4096);

    const int nChunks = ceil_div(N + 1, 256);   // 196 for N=50000 (<=256 required)
    const int tiles = ceil_div(N, 64);
    const int fillB = ceil_div(E, 256);

    prep_kernel<<<256, 256, 0, stream>>>(W1, W2, Wout, W1hi, W2hi, Wohi,
                                         cursor, stat, N, nChunks);
    hist_kernel<<<ceil_div(E, 256), 256, 0, stream>>>(dst, cursor, E);
    scan_fuse_kernel<<<nChunks, 256, 0, stream>>>(cursor, rp, cursor, stat, N);
    fill_gemm1_kernel<<<fillB + tiles, 256, 0, stream>>>(src, dst, cursor, es, E,
                                                         x, (const uint4*)W1hi, b1,
                                                         mA, N, fillB);

    fused_agg_gemm_kernel<128, false><<<tiles, 256, 0, stream>>>(
        mA, rp, es, (const uint4*)W1hi, b1, mB, N, 0);
    fused_agg_gemm_kernel<128, false><<<tiles, 256, 0, stream>>>(
        mB, rp, es, (const uint4*)W2hi, b2, mA, N, 1);   // ReLU
    fused_agg_gemm_kernel<128, false><<<tiles, 256, 0, stream>>>(
        mA, rp, es, (const uint4*)W2hi, b2, mB, N, 0);
    fused_agg_gemm_kernel<64, true><<<tiles, 256, 0, stream>>>(
        mB, rp, es, (const uint4*)Wohi, bout, out, N, 1); // ReLU
}